// Round 10
// baseline (366.216 us; speedup 1.0000x reference)
//
#include <hip/hip_runtime.h>
#include <hip/hip_bf16.h>

// ---------------- problem constants ----------------
// x: [B=8, N1=4, S=64, L=8192], PATCH=128 -> Lp=64, P=128, F=256, Lout=62
// out: [8,4,64,62,1] fp32

typedef _Float16 fp16_t;
typedef _Float16 fp16x8 __attribute__((ext_vector_type(8)));
typedef __fp16 pkh2 __attribute__((ext_vector_type(2)));   // cvt_pkrtz result type
typedef float f32x4 __attribute__((ext_vector_type(4)));

// ws float-word offsets
constexpr int WOFF_CNT   = 0;     // 16 uints
constexpr int WOFF_STRAT = 16;    // 8 ints
constexpr int WOFF_CONST = 32;    // 1 float
constexpr int WOFF_VF    = 64;    // 256 floats
constexpr int WOFF_VB    = 320;   // 256 floats
constexpr int WOFF_W1T   = 1024;                // f16 [2][4][256][32]
constexpr int WOFF_CWT   = WOFF_W1T + 32768;    // f16 [2][24][256][32]

constexpr int HBUF = 66 * 512;    // 33792 B per s-half, rows 512B XOR-swizzled

__device__ __forceinline__ float silu_f(float v) {
    return v / (1.0f + __expf(-v));
}

// ---------------- decide stage: raw-space corr counting (verified R9) ----------
__global__ __launch_bounds__(256) void rowcount_kernel(const float* __restrict__ c,
                                                       float* __restrict__ wsf) {
    const int bs = blockIdx.x;
    const int b = bs >> 6, s = bs & 63;
    const int tid = threadIdx.x;
    unsigned int* cnts = (unsigned int*)wsf + WOFF_CNT;
    const float* cb = c + (size_t)b * 65536;

    __shared__ __align__(16) float rowv[1024];
    __shared__ float ms_sh, ss_sh;
    *(float4*)&rowv[tid * 4] = *(const float4*)&cb[s * 1024 + tid * 4];
    __syncthreads();

    const int t = tid >> 2, part = tid & 3;
    const float4* src  = (const float4*)(cb + t * 1024 + part * 256);
    const float4* mine = (const float4*)(rowv + part * 256);
    float dot = 0.0f, sum = 0.0f, sq = 0.0f;
    #pragma unroll 8
    for (int i = 0; i < 64; ++i) {
        float4 a = mine[i];
        float4 bb = src[i];
        dot += a.x * bb.x + a.y * bb.y + a.z * bb.z + a.w * bb.w;
        sum += bb.x + bb.y + bb.z + bb.w;
        sq  += bb.x * bb.x + bb.y * bb.y + bb.z * bb.z + bb.w * bb.w;
    }
    dot += __shfl_down(dot, 2); dot += __shfl_down(dot, 1);
    sum += __shfl_down(sum, 2); sum += __shfl_down(sum, 1);
    sq  += __shfl_down(sq, 2);  sq  += __shfl_down(sq, 1);

    float mt = 0.0f, st = 0.0f;
    if (part == 0) {
        mt = sum * (1.0f / 1024.0f);
        st = sqrtf(fmaxf((sq - 1024.0f * mt * mt) * (1.0f / 1023.0f), 0.0f));
        if (t == s) { ms_sh = mt; ss_sh = st; }
    }
    __syncthreads();
    const float ms = ms_sh, ss = ss_sh;

    const bool valid = (part == 0) && (t != s);
    const float ctr = dot - 1024.0f * ms * mt;                 // 1024*cov
    unsigned long long mthr = __ballot(valid && (ctr > 0.6f * 1024.0f * ss * st));
    unsigned long long mpos = __ballot(valid && (ctr > 0.0f));
    if ((tid & 63) == 0) {
        atomicAdd(&cnts[b],     (unsigned int)__popcll(mthr));
        atomicAdd(&cnts[8 + b], (unsigned int)__popcll(mpos));
    }
}

// ---------------- parallel pack: 64 blocks (unchanged, verified) ----------------
__global__ __launch_bounds__(256) void pack_kernel(
    const float* __restrict__ W2f, const float* __restrict__ b2f,
    const float* __restrict__ W2b, const float* __restrict__ b2b,
    const float* __restrict__ Wr,  const float* __restrict__ br,
    const float* __restrict__ W1f, const float* __restrict__ W1b,
    const float* __restrict__ Cwf, const float* __restrict__ Cwb,
    float* __restrict__ wsf) {
    const int bid = blockIdx.x;
    const int tid = threadIdx.x;

    if (bid < 48) {
        const int d = bid / 24, ks = bid % 24;
        const float* Cw = d ? Cwb : Cwf;
        fp16_t* cwt = (fp16_t*)(wsf + WOFF_CWT) + d * 196608;
        const int base = ks * 32;
        const int k = base >> 8, i0 = base & 255;
        fp16x8 v[4];
        #pragma unroll
        for (int j = 0; j < 4; ++j)
            #pragma unroll
            for (int e = 0; e < 8; ++e)
                v[j][e] = (fp16_t)Cw[(tid * 256 + i0 + j * 8 + e) * 3 + k];
        fp16x8* dst = (fp16x8*)(cwt + (ks * 256 + tid) * 32);
        dst[0] = v[0]; dst[1] = v[1]; dst[2] = v[2]; dst[3] = v[3];
    } else if (bid < 56) {
        const int sl = bid - 48;
        const int d = sl >> 2, ks = sl & 3;
        const float* W1 = d ? W1b : W1f;
        fp16_t* w1t = (fp16_t*)(wsf + WOFF_W1T) + d * 32768;
        fp16x8 v[4];
        #pragma unroll
        for (int j = 0; j < 4; ++j)
            #pragma unroll
            for (int e = 0; e < 8; ++e)
                v[j][e] = (fp16_t)W1[(ks * 32 + j * 8 + e) * 256 + tid];
        fp16x8* dst = (fp16x8*)(w1t + (ks * 256 + tid) * 32);
        dst[0] = v[0]; dst[1] = v[1]; dst[2] = v[2]; dst[3] = v[3];
    } else {
        const int vb = bid - 56;
        const int d = vb >> 2, q = vb & 3;
        const int w = tid >> 6, lane = tid & 63;
        const float* W2 = d ? W2b : W2f;
        float4 wr4 = ((const float4*)Wr)[lane];
        for (int it = 0; it < 16; ++it) {
            int row = q * 64 + w * 16 + it;
            float4 a = ((const float4*)(W2 + row * 256))[lane];
            float p = a.x * wr4.x + a.y * wr4.y + a.z * wr4.z + a.w * wr4.w;
            #pragma unroll
            for (int off = 32; off > 0; off >>= 1) p += __shfl_down(p, off);
            if (lane == 0) wsf[(d ? WOFF_VB : WOFF_VF) + row] = p;
        }
        if (bid == 56 && tid == 0) {
            const unsigned int* cnts = (const unsigned int*)wsf + WOFF_CNT;
            int* strat = (int*)wsf + WOFF_STRAT;
            float cc = 0.0f;
            for (int g = 0; g < 256; ++g) cc += (b2f[g] + b2b[g]) * Wr[g];
            wsf[WOFF_CONST] = cc + br[0];
            for (int bb = 0; bb < 8; ++bb) {
                unsigned int ct = cnts[bb], cp = cnts[8 + bb];
                unsigned int denom = cp < 1u ? 1u : cp;
                float ratio = (cp > 0u) ? ((float)ct / (float)denom) : 0.0f;
                strat[bb] = (ratio >= 0.4f) ? 1 : 0;
            }
        }
    }
}

// ---------------- fused main: LDS tok staging + deep conv prefetch -------------
// grid 1024 = (b, n, sp); 4 waves; wave w owns output cols [64w, 64w+64).
// Per dir: stage tok f16 -> LDS (overlaid on hb0, 32KB) -> GEMM1 (acc in regs)
//          -> h-write (overwrites tok) -> conv with depth-2 B / depth-1 A prefetch.
__global__ __launch_bounds__(256, 2) void fused_main(
    const float* __restrict__ x,
    const float* __restrict__ b1f, const float* __restrict__ Cbf,
    const float* __restrict__ b1b, const float* __restrict__ Cbb,
    const float* __restrict__ wsf,
    float* __restrict__ out) {
    __shared__ __align__(16) char hball[2 * HBUF];
    __shared__ float red[128];

    char* hb0 = hball;
    char* hb1 = hball + HBUF;

    const int tid  = threadIdx.x;
    const int w    = tid >> 6;       // 0..3
    const int lane = tid & 63;
    const int l15  = lane & 15;
    const int l4   = lane >> 4;
    const int wc   = w * 64;

    const int mb = blockIdx.x;
    const int b  = mb >> 7;
    const int n  = (mb >> 5) & 3;
    const int sp = mb & 31;
    const int s0 = sp * 2, s1 = s0 + 1;
    const size_t bn = (size_t)(b * 4 + n);

    const int strat = ((const int*)wsf)[WOFF_STRAT + b];

    if (tid < 128) red[tid] = 0.0f;
    // zero pad rows 64,65 of both buffers (conv tail reads them)
    ((unsigned int*)(hb0 + 64 * 512))[tid] = 0u;
    ((unsigned int*)(hb1 + 64 * 512))[tid] = 0u;

    const char* w1base = (const char*)(wsf + WOFF_W1T);
    const char* cwbase = (const char*)(wsf + WOFF_CWT);

    for (int dir = 0; dir < 2; ++dir) {
        const float* b1 = dir ? b1b : b1f;
        const float* cb = dir ? Cbb : Cbf;
        const char* w1sl = w1base + dir * 65536;
        const char* cwsl = cwbase + dir * 393216;

        // ---------- stage tok f16 into hball[0..32768), 256B rows, XOR-swizzled --
        __syncthreads();   // prev dir's conv h-reads done (or init writes, dir 0)
        {
            const int row  = tid >> 1;          // 0..127 (row>=64 -> s1)
            const int half = (tid & 1) * 64;    // patch-col base in floats
            const int lp   = row & 63;
            const int sv   = (row < 64) ? s0 : s1;
            const int sg   = dir ? (63 - sv) : sv;
            const int r1i  = strat ? lp : sg;
            const int r2i  = strat ? sg : lp;
            const float* src = x + ((bn * 64 + r1i) * 8192 + (size_t)r2i * 128 + half);
            const int rbase = row * 256 + half * 2;
            const int sw = (row & 7) << 4;
            #pragma unroll
            for (int j = 0; j < 8; ++j) {
                float4 p0 = *(const float4*)(src + j * 8);
                float4 p1 = *(const float4*)(src + j * 8 + 4);
                union { pkh2 h2[2]; uint2 u; } pk;
                pk.h2[0] = __builtin_amdgcn_cvt_pkrtz(p0.x, p0.y);
                pk.h2[1] = __builtin_amdgcn_cvt_pkrtz(p0.z, p0.w);
                union { pkh2 h2[2]; uint2 u; } pk2;
                pk2.h2[0] = __builtin_amdgcn_cvt_pkrtz(p1.x, p1.y);
                pk2.h2[1] = __builtin_amdgcn_cvt_pkrtz(p1.z, p1.w);
                uint4 out4 = make_uint4(pk.u.x, pk.u.y, pk2.u.x, pk2.u.y);
                *(uint4*)(hball + ((rbase + j * 16) ^ sw)) = out4;
            }
        }
        __syncthreads();   // tok ready

        // ---------- GEMM1 (swapped): h[l][f] = silu(tok@W1 + b1) ----------
        f32x4 acc1[4][8];
        #pragma unroll
        for (int i = 0; i < 4; ++i)
            #pragma unroll
            for (int j = 0; j < 8; ++j)
                acc1[i][j] = (f32x4){0.f, 0.f, 0.f, 0.f};

        #pragma unroll
        for (int ks = 0; ks < 4; ++ks) {
            fp16x8 wa[4];   // A = W1 frags (M = f) from L2
            #pragma unroll
            for (int mt = 0; mt < 4; ++mt)
                wa[mt] = *(const fp16x8*)(w1sl
                    + (ks * 256 + wc + mt * 16 + l15) * 64 + l4 * 16);
            fp16x8 tb[8];   // B = tok frags (N = l) from LDS
            #pragma unroll
            for (int t = 0; t < 8; ++t) {
                int row = (t & 3) * 16 + l15 + ((t >> 2) << 6);
                int byte = (row * 256 + ks * 64 + l4 * 16) ^ ((row & 7) << 4);
                tb[t] = *(const fp16x8*)(hball + byte);
            }
            #pragma unroll
            for (int mt = 0; mt < 4; ++mt)
                #pragma unroll
                for (int t = 0; t < 8; ++t)
                    acc1[mt][t] = __builtin_amdgcn_mfma_f32_16x16x32_f16(
                        wa[mt], tb[t], acc1[mt][t], 0, 0, 0);
        }

        // bias values for this lane's f rows
        float b1r[4][4];
        #pragma unroll
        for (int mt = 0; mt < 4; ++mt)
            #pragma unroll
            for (int q = 0; q < 4; ++q)
                b1r[mt][q] = b1[wc + mt * 16 + l4 * 4 + q];

        __syncthreads();  // all tok reads done before overwrite
        #pragma unroll
        for (int t = 0; t < 8; ++t) {
            char* hbt = (t < 4) ? hb0 : hb1;
            int l = (t & 3) * 16 + l15;
            int rowoff = l * 512;
            int sw = (l & 7) << 4;
            #pragma unroll
            for (int mt = 0; mt < 4; ++mt) {
                f32x4 a = acc1[mt][t];
                union { pkh2 h2[2]; uint2 u; } pk;
                pk.h2[0] = __builtin_amdgcn_cvt_pkrtz(
                    silu_f(a[0] + b1r[mt][0]), silu_f(a[1] + b1r[mt][1]));
                pk.h2[1] = __builtin_amdgcn_cvt_pkrtz(
                    silu_f(a[2] + b1r[mt][2]), silu_f(a[3] + b1r[mt][3]));
                int byte = (rowoff + (wc + mt * 16 + l4 * 4) * 2) ^ sw;
                *(uint2*)(hbt + byte) = pk.u;
            }
        }
        __syncthreads();  // h ready

        // ---------- conv GEMM: M=128, K=768, depth-2 B / depth-1 A prefetch -----
        f32x4 acc2[8][4];
        #pragma unroll
        for (int i = 0; i < 8; ++i)
            #pragma unroll
            for (int j = 0; j < 4; ++j)
                acc2[i][j] = (f32x4){0.f, 0.f, 0.f, 0.f};

        const char* cw_w = cwsl + (size_t)(wc + l15) * 64 + l4 * 16;
        fp16x8 bq[4], bn1[4];
        #pragma unroll
        for (int t = 0; t < 4; ++t) {
            bq[t]  = *(const fp16x8*)(cw_w + t * 1024);
            bn1[t] = *(const fp16x8*)(cw_w + 16384 + t * 1024);
        }
        fp16x8 af[8];
        {
            const int base = (l15 * 512 + l4 * 16) ^ ((l15 & 7) << 4);
            #pragma unroll
            for (int mt = 0; mt < 4; ++mt) {
                af[mt]     = *(const fp16x8*)(hb0 + base + mt * 8192);
                af[mt + 4] = *(const fp16x8*)(hb1 + base + mt * 8192);
            }
        }

        for (int ks = 0; ks < 24; ++ks) {
            fp16x8 bn2[4];
            if (ks < 22) {
                #pragma unroll
                for (int t = 0; t < 4; ++t)
                    bn2[t] = *(const fp16x8*)(cw_w + (ks + 2) * 16384 + t * 1024);
            }
            fp16x8 afn[8];
            if (ks < 23) {
                const int brow = l15 + ((ks + 1) >> 3);
                const int base = (brow * 512 + ((ks + 1) & 7) * 64 + l4 * 16)
                                 ^ ((brow & 7) << 4);
                #pragma unroll
                for (int mt = 0; mt < 4; ++mt) {
                    afn[mt]     = *(const fp16x8*)(hb0 + base + mt * 8192);
                    afn[mt + 4] = *(const fp16x8*)(hb1 + base + mt * 8192);
                }
            }
            #pragma unroll
            for (int t = 0; t < 4; ++t)
                #pragma unroll
                for (int mt = 0; mt < 8; ++mt)
                    acc2[mt][t] = __builtin_amdgcn_mfma_f32_16x16x32_f16(
                        af[mt], bq[t], acc2[mt][t], 0, 0, 0);
            #pragma unroll
            for (int mt = 0; mt < 8; ++mt) af[mt] = afn[mt];
            #pragma unroll
            for (int t = 0; t < 4; ++t) { bq[t] = bn1[t]; bn1[t] = bn2[t]; }
        }

        // epilogue: silu(conv + cb) * v, reduce over o -> red
        float cbv[4], vv[4];
        #pragma unroll
        for (int t = 0; t < 4; ++t) {
            int col = wc + t * 16 + l15;
            cbv[t] = cb[col];
            vv[t]  = wsf[(dir ? WOFF_VB : WOFF_VF) + col];
        }
        #pragma unroll
        for (int mt = 0; mt < 8; ++mt) {
            #pragma unroll
            for (int q = 0; q < 4; ++q) {
                float v0 = 0.f;
                #pragma unroll
                for (int t = 0; t < 4; ++t)
                    v0 += silu_f(acc2[mt][t][q] + cbv[t]) * vv[t];
                v0 += __shfl_xor(v0, 1);
                v0 += __shfl_xor(v0, 2);
                v0 += __shfl_xor(v0, 4);
                v0 += __shfl_xor(v0, 8);
                if (l15 == 0) {
                    int idx = (mt >> 2) * 64 + (mt & 3) * 16 + l4 * 4 + q;
                    atomicAdd(&red[idx], v0);
                }
            }
        }
    }

    __syncthreads();
    const float constv = wsf[WOFF_CONST];
    if (tid < 62)
        out[(bn * 64 + s0) * 62 + tid] = red[tid] + constv;
    if (tid >= 64 && tid < 126)
        out[(bn * 64 + s1) * 62 + (tid - 64)] = red[tid] + constv;
}

extern "C" void kernel_launch(void* const* d_in, const int* in_sizes, int n_in,
                              void* d_out, int out_size, void* d_ws, size_t ws_size,
                              hipStream_t stream) {
    (void)in_sizes; (void)n_in; (void)out_size; (void)ws_size;
    const float* x    = (const float*)d_in[0];
    const float* corr = (const float*)d_in[1];
    const float* W1f  = (const float*)d_in[2];
    const float* b1f  = (const float*)d_in[3];
    const float* Cwf  = (const float*)d_in[4];
    const float* Cbf  = (const float*)d_in[5];
    const float* W2f  = (const float*)d_in[6];
    const float* b2f  = (const float*)d_in[7];
    const float* W1b  = (const float*)d_in[8];
    const float* b1b  = (const float*)d_in[9];
    const float* Cwb  = (const float*)d_in[10];
    const float* Cbb  = (const float*)d_in[11];
    const float* W2b  = (const float*)d_in[12];
    const float* b2b  = (const float*)d_in[13];
    const float* Wr   = (const float*)d_in[14];
    const float* br   = (const float*)d_in[15];
    float* out = (float*)d_out;
    float* wsf = (float*)d_ws;

    hipMemsetAsync(wsf + WOFF_CNT, 0, 16 * sizeof(unsigned int), stream);
    rowcount_kernel<<<512, 256, 0, stream>>>(corr, wsf);
    pack_kernel<<<64, 256, 0, stream>>>(W2f, b2f, W2b, b2b, Wr, br,
                                        W1f, W1b, Cwf, Cwb, wsf);
    fused_main<<<1024, 256, 0, stream>>>(x, b1f, Cbf, b1b, Cbb, wsf, out);
}

// Round 12
// 245.199 us; speedup vs baseline: 1.4935x; 1.4935x over previous
//
#include <hip/hip_runtime.h>
#include <hip/hip_bf16.h>

// ---------------- problem constants ----------------
// x: [B=8, N1=4, S=64, L=8192], PATCH=128 -> Lp=64, P=128, F=256, Lout=62
// out: [8,4,64,62,1] fp32

typedef _Float16 fp16_t;
typedef _Float16 fp16x8 __attribute__((ext_vector_type(8)));
typedef __fp16 pkh2 __attribute__((ext_vector_type(2)));   // cvt_pkrtz result type
typedef float f32x4 __attribute__((ext_vector_type(4)));

// ws float-word offsets
constexpr int WOFF_CNT   = 0;     // 16 uints
constexpr int WOFF_STRAT = 16;    // 8 ints
constexpr int WOFF_CONST = 32;    // 1 float
constexpr int WOFF_VF    = 64;    // 256 floats
constexpr int WOFF_VB    = 320;   // 256 floats
constexpr int WOFF_W1T   = 1024;                // f16 [2][4][256][32]
constexpr int WOFF_CWT   = WOFF_W1T + 32768;    // f16 [2][24][256][32]

__device__ __forceinline__ float silu_f(float v) {
    return v / (1.0f + __expf(-v));
}

// ---------------- decide stage: raw-space corr counting (verified R9) ----------
__global__ __launch_bounds__(256) void rowcount_kernel(const float* __restrict__ c,
                                                       float* __restrict__ wsf) {
    const int bs = blockIdx.x;
    const int b = bs >> 6, s = bs & 63;
    const int tid = threadIdx.x;
    unsigned int* cnts = (unsigned int*)wsf + WOFF_CNT;
    const float* cb = c + (size_t)b * 65536;

    __shared__ __align__(16) float rowv[1024];
    __shared__ float ms_sh, ss_sh;
    *(float4*)&rowv[tid * 4] = *(const float4*)&cb[s * 1024 + tid * 4];
    __syncthreads();

    const int t = tid >> 2, part = tid & 3;
    const float4* src  = (const float4*)(cb + t * 1024 + part * 256);
    const float4* mine = (const float4*)(rowv + part * 256);
    float dot = 0.0f, sum = 0.0f, sq = 0.0f;
    #pragma unroll 8
    for (int i = 0; i < 64; ++i) {
        float4 a = mine[i];
        float4 bb = src[i];
        dot += a.x * bb.x + a.y * bb.y + a.z * bb.z + a.w * bb.w;
        sum += bb.x + bb.y + bb.z + bb.w;
        sq  += bb.x * bb.x + bb.y * bb.y + bb.z * bb.z + bb.w * bb.w;
    }
    dot += __shfl_down(dot, 2); dot += __shfl_down(dot, 1);
    sum += __shfl_down(sum, 2); sum += __shfl_down(sum, 1);
    sq  += __shfl_down(sq, 2);  sq  += __shfl_down(sq, 1);

    float mt = 0.0f, st = 0.0f;
    if (part == 0) {
        mt = sum * (1.0f / 1024.0f);
        st = sqrtf(fmaxf((sq - 1024.0f * mt * mt) * (1.0f / 1023.0f), 0.0f));
        if (t == s) { ms_sh = mt; ss_sh = st; }
    }
    __syncthreads();
    const float ms = ms_sh, ss = ss_sh;

    const bool valid = (part == 0) && (t != s);
    const float ctr = dot - 1024.0f * ms * mt;                 // 1024*cov
    unsigned long long mthr = __ballot(valid && (ctr > 0.6f * 1024.0f * ss * st));
    unsigned long long mpos = __ballot(valid && (ctr > 0.0f));
    if ((tid & 63) == 0) {
        atomicAdd(&cnts[b],     (unsigned int)__popcll(mthr));
        atomicAdd(&cnts[8 + b], (unsigned int)__popcll(mpos));
    }
}

// ---------------- parallel pack: 64 blocks (unchanged, verified) ----------------
__global__ __launch_bounds__(256) void pack_kernel(
    const float* __restrict__ W2f, const float* __restrict__ b2f,
    const float* __restrict__ W2b, const float* __restrict__ b2b,
    const float* __restrict__ Wr,  const float* __restrict__ br,
    const float* __restrict__ W1f, const float* __restrict__ W1b,
    const float* __restrict__ Cwf, const float* __restrict__ Cwb,
    float* __restrict__ wsf) {
    const int bid = blockIdx.x;
    const int tid = threadIdx.x;

    if (bid < 48) {
        const int d = bid / 24, ks = bid % 24;
        const float* Cw = d ? Cwb : Cwf;
        fp16_t* cwt = (fp16_t*)(wsf + WOFF_CWT) + d * 196608;
        const int base = ks * 32;
        const int k = base >> 8, i0 = base & 255;
        fp16x8 v[4];
        #pragma unroll
        for (int j = 0; j < 4; ++j)
            #pragma unroll
            for (int e = 0; e < 8; ++e)
                v[j][e] = (fp16_t)Cw[(tid * 256 + i0 + j * 8 + e) * 3 + k];
        fp16x8* dst = (fp16x8*)(cwt + (ks * 256 + tid) * 32);
        dst[0] = v[0]; dst[1] = v[1]; dst[2] = v[2]; dst[3] = v[3];
    } else if (bid < 56) {
        const int sl = bid - 48;
        const int d = sl >> 2, ks = sl & 3;
        const float* W1 = d ? W1b : W1f;
        fp16_t* w1t = (fp16_t*)(wsf + WOFF_W1T) + d * 32768;
        fp16x8 v[4];
        #pragma unroll
        for (int j = 0; j < 4; ++j)
            #pragma unroll
            for (int e = 0; e < 8; ++e)
                v[j][e] = (fp16_t)W1[(ks * 32 + j * 8 + e) * 256 + tid];
        fp16x8* dst = (fp16x8*)(w1t + (ks * 256 + tid) * 32);
        dst[0] = v[0]; dst[1] = v[1]; dst[2] = v[2]; dst[3] = v[3];
    } else {
        const int vb = bid - 56;
        const int d = vb >> 2, q = vb & 3;
        const int w = tid >> 6, lane = tid & 63;
        const float* W2 = d ? W2b : W2f;
        float4 wr4 = ((const float4*)Wr)[lane];
        for (int it = 0; it < 16; ++it) {
            int row = q * 64 + w * 16 + it;
            float4 a = ((const float4*)(W2 + row * 256))[lane];
            float p = a.x * wr4.x + a.y * wr4.y + a.z * wr4.z + a.w * wr4.w;
            #pragma unroll
            for (int off = 32; off > 0; off >>= 1) p += __shfl_down(p, off);
            if (lane == 0) wsf[(d ? WOFF_VB : WOFF_VF) + row] = p;
        }
        if (bid == 56 && tid == 0) {
            const unsigned int* cnts = (const unsigned int*)wsf + WOFF_CNT;
            int* strat = (int*)wsf + WOFF_STRAT;
            float cc = 0.0f;
            for (int g = 0; g < 256; ++g) cc += (b2f[g] + b2b[g]) * Wr[g];
            wsf[WOFF_CONST] = cc + br[0];
            for (int bb = 0; bb < 8; ++bb) {
                unsigned int ct = cnts[bb], cp = cnts[8 + bb];
                unsigned int denom = cp < 1u ? 1u : cp;
                float ratio = (cp > 0u) ? ((float)ct / (float)denom) : 0.0f;
                strat[bb] = (ratio >= 0.4f) ? 1 : 0;
            }
        }
    }
}

// ---------------- fused main: one (b,n,s,dir) per block -------------------------
// grid 4096: dir = mb&1, s = (mb>>1)&63, bn = mb>>7. 4 waves; wave w owns cols
// [64w, 64w+64). M=64 rows. LDS: one h buffer (34KB) -> 4 blocks/CU, 16 waves/CU.
// Both dir-blocks atomicAdd into pre-zeroed out (2 commutative adds, deterministic).
__global__ __launch_bounds__(256, 4) void fused_main(
    const float* __restrict__ x,
    const float* __restrict__ b1f, const float* __restrict__ Cbf,
    const float* __restrict__ b1b, const float* __restrict__ Cbb,
    const float* __restrict__ wsf,
    float* __restrict__ out) {
    __shared__ __align__(16) char hb[66 * 512];   // h [66 rows][512B], XOR-swizzled
    __shared__ float red[64];

    const int tid  = threadIdx.x;
    const int w    = tid >> 6;       // 0..3
    const int lane = tid & 63;
    const int l15  = lane & 15;
    const int l4   = lane >> 4;
    const int wc   = w * 64;

    const int mb  = blockIdx.x;
    const int dir = mb & 1;
    const int s   = (mb >> 1) & 63;
    const int bn  = mb >> 7;         // 0..31
    const int sg  = dir ? (63 - s) : s;

    const int strat = ((const int*)wsf)[WOFF_STRAT + (bn >> 2)];  // b = bn>>2 (R11 bug: precedence)
    const float* b1 = dir ? b1b : b1f;
    const float* cbp = dir ? Cbb : Cbf;
    const char* w1sl = (const char*)(wsf + WOFF_W1T) + dir * 65536;
    const char* cwsl = (const char*)(wsf + WOFF_CWT) + dir * 393216;

    if (tid < 64) red[tid] = 0.0f;
    ((unsigned int*)(hb + 64 * 512))[tid] = 0u;   // zero pad rows 64,65 (1KB)

    // ---------- stage tok f16 into hb[0..16KB), 256B rows, XOR-swizzled ----------
    {
        const int row = tid >> 2;          // 0..63  (= lp)
        const int qtr = tid & 3;           // 32-float chunk
        const int r1i = strat ? row : sg;
        const int r2i = strat ? sg : row;
        const float* src = x + (((size_t)bn * 64 + r1i) * 8192
                                + (size_t)r2i * 128 + qtr * 32);
        const int rbase = row * 256 + qtr * 64;
        const int sw = (row & 7) << 4;
        #pragma unroll
        for (int j = 0; j < 4; ++j) {
            float4 p0 = *(const float4*)(src + j * 8);
            float4 p1 = *(const float4*)(src + j * 8 + 4);
            union { pkh2 h2[2]; uint2 u; } pa, pb;
            pa.h2[0] = __builtin_amdgcn_cvt_pkrtz(p0.x, p0.y);
            pa.h2[1] = __builtin_amdgcn_cvt_pkrtz(p0.z, p0.w);
            pb.h2[0] = __builtin_amdgcn_cvt_pkrtz(p1.x, p1.y);
            pb.h2[1] = __builtin_amdgcn_cvt_pkrtz(p1.z, p1.w);
            uint4 o4 = make_uint4(pa.u.x, pa.u.y, pb.u.x, pb.u.y);
            *(uint4*)(hb + ((rbase + j * 16) ^ sw)) = o4;
        }
    }
    __syncthreads();   // tok ready

    // ---------- GEMM1 (swapped): h[l][f] = silu(tok@W1 + b1) ----------
    f32x4 acc1[4][4];
    #pragma unroll
    for (int i = 0; i < 4; ++i)
        #pragma unroll
        for (int j = 0; j < 4; ++j)
            acc1[i][j] = (f32x4){0.f, 0.f, 0.f, 0.f};

    #pragma unroll
    for (int ks = 0; ks < 4; ++ks) {
        fp16x8 wa[4];   // A = W1 frags (M = f) from L2
        #pragma unroll
        for (int mt = 0; mt < 4; ++mt)
            wa[mt] = *(const fp16x8*)(w1sl
                + (ks * 256 + wc + mt * 16 + l15) * 64 + l4 * 16);
        fp16x8 tb[4];   // B = tok frags (N = l) from LDS
        #pragma unroll
        for (int t = 0; t < 4; ++t) {
            int row = t * 16 + l15;
            int byte = (row * 256 + ks * 64 + l4 * 16) ^ ((row & 7) << 4);
            tb[t] = *(const fp16x8*)(hb + byte);
        }
        #pragma unroll
        for (int mt = 0; mt < 4; ++mt)
            #pragma unroll
            for (int t = 0; t < 4; ++t)
                acc1[mt][t] = __builtin_amdgcn_mfma_f32_16x16x32_f16(
                    wa[mt], tb[t], acc1[mt][t], 0, 0, 0);
    }

    float b1r[4][4];
    #pragma unroll
    for (int mt = 0; mt < 4; ++mt)
        #pragma unroll
        for (int q = 0; q < 4; ++q)
            b1r[mt][q] = b1[wc + mt * 16 + l4 * 4 + q];

    __syncthreads();  // all tok reads done before overwrite
    #pragma unroll
    for (int t = 0; t < 4; ++t) {
        int l = t * 16 + l15;
        int rowoff = l * 512;
        int sw = (l & 7) << 4;
        #pragma unroll
        for (int mt = 0; mt < 4; ++mt) {
            f32x4 a = acc1[mt][t];
            union { pkh2 h2[2]; uint2 u; } pk;
            pk.h2[0] = __builtin_amdgcn_cvt_pkrtz(
                silu_f(a[0] + b1r[mt][0]), silu_f(a[1] + b1r[mt][1]));
            pk.h2[1] = __builtin_amdgcn_cvt_pkrtz(
                silu_f(a[2] + b1r[mt][2]), silu_f(a[3] + b1r[mt][3]));
            int byte = (rowoff + (wc + mt * 16 + l4 * 4) * 2) ^ sw;
            *(uint2*)(hb + byte) = pk.u;
        }
    }
    __syncthreads();  // h ready

    // ---------- conv GEMM: M=64, K=768, 24 slices, depth-1 B prefetch ----------
    f32x4 acc2[4][4];
    #pragma unroll
    for (int i = 0; i < 4; ++i)
        #pragma unroll
        for (int j = 0; j < 4; ++j)
            acc2[i][j] = (f32x4){0.f, 0.f, 0.f, 0.f};

    const char* cw_w = cwsl + (size_t)(wc + l15) * 64 + l4 * 16;
    fp16x8 bq[4];
    #pragma unroll
    for (int t = 0; t < 4; ++t)
        bq[t] = *(const fp16x8*)(cw_w + t * 1024);

    for (int ks = 0; ks < 24; ++ks) {
        fp16x8 bnx[4];
        if (ks < 23) {
            #pragma unroll
            for (int t = 0; t < 4; ++t)
                bnx[t] = *(const fp16x8*)(cw_w + (ks + 1) * 16384 + t * 1024);
        }
        const int brow = l15 + (ks >> 3);
        const int base = (brow * 512 + (ks & 7) * 64 + l4 * 16)
                         ^ ((brow & 7) << 4);
        fp16x8 af[4];
        #pragma unroll
        for (int mt = 0; mt < 4; ++mt)
            af[mt] = *(const fp16x8*)(hb + base + mt * 8192);
        #pragma unroll
        for (int t = 0; t < 4; ++t)
            #pragma unroll
            for (int mt = 0; mt < 4; ++mt)
                acc2[mt][t] = __builtin_amdgcn_mfma_f32_16x16x32_f16(
                    af[mt], bq[t], acc2[mt][t], 0, 0, 0);
        #pragma unroll
        for (int t = 0; t < 4; ++t) bq[t] = bnx[t];
    }

    // epilogue: silu(conv + cb) * v, reduce over o -> red
    float cbv[4], vv[4];
    #pragma unroll
    for (int t = 0; t < 4; ++t) {
        int col = wc + t * 16 + l15;
        cbv[t] = cbp[col];
        vv[t]  = wsf[(dir ? WOFF_VB : WOFF_VF) + col];
    }
    #pragma unroll
    for (int mt = 0; mt < 4; ++mt) {
        #pragma unroll
        for (int q = 0; q < 4; ++q) {
            float v0 = 0.f;
            #pragma unroll
            for (int t = 0; t < 4; ++t)
                v0 += silu_f(acc2[mt][t][q] + cbv[t]) * vv[t];
            v0 += __shfl_xor(v0, 1);
            v0 += __shfl_xor(v0, 2);
            v0 += __shfl_xor(v0, 4);
            v0 += __shfl_xor(v0, 8);
            if (l15 == 0) atomicAdd(&red[mt * 16 + l4 * 4 + q], v0);
        }
    }

    __syncthreads();
    if (tid < 62) {
        float add = red[tid] + (dir ? 0.0f : wsf[WOFF_CONST]);
        atomicAdd(&out[((size_t)bn * 64 + s) * 62 + tid], add);
    }
}

extern "C" void kernel_launch(void* const* d_in, const int* in_sizes, int n_in,
                              void* d_out, int out_size, void* d_ws, size_t ws_size,
                              hipStream_t stream) {
    (void)in_sizes; (void)n_in; (void)ws_size;
    const float* x    = (const float*)d_in[0];
    const float* corr = (const float*)d_in[1];
    const float* W1f  = (const float*)d_in[2];
    const float* b1f  = (const float*)d_in[3];
    const float* Cwf  = (const float*)d_in[4];
    const float* Cbf  = (const float*)d_in[5];
    const float* W2f  = (const float*)d_in[6];
    const float* b2f  = (const float*)d_in[7];
    const float* W1b  = (const float*)d_in[8];
    const float* b1b  = (const float*)d_in[9];
    const float* Cwb  = (const float*)d_in[10];
    const float* Cbb  = (const float*)d_in[11];
    const float* W2b  = (const float*)d_in[12];
    const float* b2b  = (const float*)d_in[13];
    const float* Wr   = (const float*)d_in[14];
    const float* br   = (const float*)d_in[15];
    float* out = (float*)d_out;
    float* wsf = (float*)d_ws;

    hipMemsetAsync(wsf + WOFF_CNT, 0, 16 * sizeof(unsigned int), stream);
    hipMemsetAsync(out, 0, (size_t)out_size * sizeof(float), stream);
    rowcount_kernel<<<512, 256, 0, stream>>>(corr, wsf);
    pack_kernel<<<64, 256, 0, stream>>>(W2f, b2f, W2b, b2b, Wr, br,
                                        W1f, W1b, Cwf, Cwb, wsf);
    fused_main<<<4096, 256, 0, stream>>>(x, b1f, Cbf, b1b, Cbb, wsf, out);
}